// Round 14
// baseline (406.550 us; speedup 1.0000x reference)
//
#include <hip/hip_runtime.h>
#include <hip/hip_cooperative_groups.h>
#include <math.h>

namespace cg = cooperative_groups;

#define N_NODES 50000
#define E_EDGES 300000
#define E_TOT   350000   // E + N self-loops
#define NEG 0.2f
#define EPS 1e-16f
#define SCAN_BLOCKS 196  // 196*256 = 50176 >= 50000

typedef __attribute__((ext_vector_type(8))) short bf16x8;
typedef __attribute__((ext_vector_type(4))) float f32x4;

__device__ __forceinline__ float leaky(float x) { return x > 0.f ? x : NEG * x; }
// fp32 -> bf16 (RNE, finite inputs)
__device__ __forceinline__ short f2bf(float v) {
    unsigned u = __float_as_uint(v);
    u += 0x7fffu + ((u >> 16) & 1u);
    return (short)(u >> 16);
}
__device__ __forceinline__ float bflo(unsigned u) { return __uint_as_float(u << 16); }
__device__ __forceinline__ float bfhi(unsigned u) { return __uint_as_float(u & 0xffff0000u); }

// ---------------- cooperative: CSR build + weight prep + s1 (one launch) -----
// 196 blocks x 256. Phases separated by grid.sync():
// P0 zero deg + W1b/W2bT/wsv prep | P1 hist + s1 | P2 block scan | P3 scan of
// block sums (block 0) | P4 rowptr/cursor | P5 scatter.
__global__ __launch_bounds__(256) void k_csr_prep(
        const int* __restrict__ ei, const float* __restrict__ x,
        const float* __restrict__ W1, const float* __restrict__ as1,
        const float* __restrict__ ad1, const float* __restrict__ W2,
        int* deg, int* rowptr, int* cursor, int* eidx,
        float* wsv, short* W1b, short* W2bT, float* s1,
        int* bsum, int* bofs) {
    cg::grid_group grid = cg::this_grid();
    __shared__ int sh[256];
    int t = threadIdx.x;
    int gt = blockIdx.x * 256 + t;               // 0..50175
    const int GSZ = SCAN_BLOCKS * 256;

    // P0: zero deg + weight prep
    if (gt < N_NODES) deg[gt] = 0;
    for (int i = gt; i < 32768; i += GSZ) {      // W2bT[col][k] = W2[k][col]
        int col = i >> 8, k = i & 255;
        W2bT[i] = f2bf(W2[k * 128 + col]);
    }
    for (int i = gt; i < 8192; i += GSZ) {       // W1b[h][col][k], k pad 27->32
        int h = i >> 11, col = (i >> 5) & 63, k = i & 31;
        W1b[i] = f2bf(k < 27 ? W1[k * 256 + h * 64 + col] : 0.f);
    }
    if (gt < 216) {                              // wsv[k][j] = W1 row . a
        int k = gt >> 3, j = gt & 7;
        const float* av = (j < 4) ? (as1 + j * 64) : (ad1 + (j - 4) * 64);
        const float* wr = W1 + k * 256 + ((j & 3) * 64);
        float s = 0.f;
        for (int d = 0; d < 64; ++d) s += wr[d] * av[d];
        wsv[k * 8 + j] = s;
    }
    __threadfence();
    grid.sync();

    // P1: histogram + s1 GEMV (s1[n][0..3]=src, [4..7]=dst)
    for (int e = gt; e < E_TOT; e += GSZ) {
        int d = (e < E_EDGES) ? ei[E_EDGES + e] : (e - E_EDGES);
        atomicAdd(&deg[d], 1);
    }
    for (int i = gt; i < N_NODES * 8; i += GSZ) {
        int n = i >> 3, j = i & 7;
        float s = 0.f;
        #pragma unroll
        for (int k = 0; k < 27; ++k) s += x[n * 27 + k] * wsv[k * 8 + j];
        s1[i] = s;
    }
    __threadfence();
    grid.sync();

    // P2: block-local inclusive scan over this block's 256 deg entries
    int myv = (gt < N_NODES) ? deg[gt] : 0;
    sh[t] = myv;
    __syncthreads();
    for (int s = 1; s < 256; s <<= 1) {
        int u = (t >= s) ? sh[t - s] : 0;
        __syncthreads();
        sh[t] += u;
        __syncthreads();
    }
    int lexcl = sh[t] - myv;                     // block-local exclusive
    if (t == 255) bsum[blockIdx.x] = sh[255];
    __threadfence();
    grid.sync();

    // P3: block 0 scans the 196 block sums -> exclusive bofs
    if (blockIdx.x == 0) {
        int v = (t < SCAN_BLOCKS) ? bsum[t] : 0;
        sh[t] = v;
        __syncthreads();
        for (int s = 1; s < 256; s <<= 1) {
            int u = (t >= s) ? sh[t - s] : 0;
            __syncthreads();
            sh[t] += u;
            __syncthreads();
        }
        bofs[t] = sh[t] - v;
        __threadfence();
    }
    grid.sync();

    // P4: rowptr / cursor
    int excl = lexcl + bofs[blockIdx.x];
    if (gt < N_NODES) { rowptr[gt] = excl; cursor[gt] = excl; }
    if (gt == N_NODES) rowptr[N_NODES] = E_TOT;
    __threadfence();
    grid.sync();

    // P5: scatter src indices into CSR order
    for (int e = gt; e < E_TOT; e += GSZ) {
        int s = (e < E_EDGES) ? ei[e] : (e - E_EDGES);
        int d = (e < E_EDGES) ? ei[E_EDGES + e] : (e - E_EDGES);
        int pos = atomicAdd(&cursor[d], 1);
        eidx[pos] = s;
    }
}

// ---------------- fused layer-1 agg (x-space) + expand + GEMM2 ----------------
// (R11 proven version) Block = 16 nodes; Phase A gather (4x unroll), Phase B
// expand head w via MFMA + elu -> LDS, Phase C GEMM2 (K=256) + s2.
__global__ __launch_bounds__(256) void k_fused1(const int* __restrict__ rowptr,
        const int* __restrict__ eidx, const float* __restrict__ x,
        const float* __restrict__ s1, const short* __restrict__ W1b,
        const short* __restrict__ W2bT, const float* __restrict__ b1,
        const float* __restrict__ as2, const float* __restrict__ ad2,
        short* __restrict__ h2b, float* __restrict__ s2) {
    __shared__ short LDSx[4 * 16 * 32];          // [head][m][k] bf16
    __shared__ short O[16 * 264];                // out1' [m][col], padded stride
    __shared__ float P[4][2][16];                // s2 partials [wave][ps/pd][m]
    int w = threadIdx.x >> 6, l = threadIdx.x & 63;
    int n0 = blockIdx.x * 16;                    // grid 3125 -> 50000 exact
    int h5 = l >> 5, c = l & 31;                 // half-wave, channel slot
    f32x4 z4 = {0.f, 0.f, 0.f, 0.f};

    for (int r = 0; r < 2; ++r) {
        int m = w * 4 + r * 2 + h5;
        int n = n0 + m;
        int beg = rowptr[n];
        int deg = rowptr[n + 1] - beg;
        int degmax = max(deg, __shfl_xor(deg, 32));
        float4 sdv = *(const float4*)(s1 + n * 8 + 4);
        float a0 = 0.f, a1 = 0.f, a2 = 0.f, a3 = 0.f;
        float z0 = 0.f, z1 = 0.f, z2 = 0.f, z3 = 0.f;
        int i = 0;
        for (; i + 4 <= degmax; i += 4) {
            bool c0 = (i + 0) < deg, c1 = (i + 1) < deg;
            bool c2 = (i + 2) < deg, c3 = (i + 3) < deg;
            int s0 = c0 ? eidx[beg + i + 0] : n;
            int s1i = c1 ? eidx[beg + i + 1] : n;
            int s2i = c2 ? eidx[beg + i + 2] : n;
            int s3 = c3 ? eidx[beg + i + 3] : n;
            float4 sv0 = *(const float4*)(s1 + s0 * 8);
            float4 sv1 = *(const float4*)(s1 + s1i * 8);
            float4 sv2 = *(const float4*)(s1 + s2i * 8);
            float4 sv3 = *(const float4*)(s1 + s3 * 8);
            float xv0 = (c0 && c < 27) ? x[s0 * 27 + c] : 0.f;
            float xv1 = (c1 && c < 27) ? x[s1i * 27 + c] : 0.f;
            float xv2 = (c2 && c < 27) ? x[s2i * 27 + c] : 0.f;
            float xv3 = (c3 && c < 27) ? x[s3 * 27 + c] : 0.f;
            float g0 = c0 ? 1.f : 0.f, g1 = c1 ? 1.f : 0.f;
            float g2 = c2 ? 1.f : 0.f, g3 = c3 ? 1.f : 0.f;
            float e00 = g0 * __expf(leaky(sv0.x + sdv.x));
            float e01 = g0 * __expf(leaky(sv0.y + sdv.y));
            float e02 = g0 * __expf(leaky(sv0.z + sdv.z));
            float e03 = g0 * __expf(leaky(sv0.w + sdv.w));
            float e10 = g1 * __expf(leaky(sv1.x + sdv.x));
            float e11 = g1 * __expf(leaky(sv1.y + sdv.y));
            float e12 = g1 * __expf(leaky(sv1.z + sdv.z));
            float e13 = g1 * __expf(leaky(sv1.w + sdv.w));
            float e20 = g2 * __expf(leaky(sv2.x + sdv.x));
            float e21 = g2 * __expf(leaky(sv2.y + sdv.y));
            float e22 = g2 * __expf(leaky(sv2.z + sdv.z));
            float e23 = g2 * __expf(leaky(sv2.w + sdv.w));
            float e30 = g3 * __expf(leaky(sv3.x + sdv.x));
            float e31 = g3 * __expf(leaky(sv3.y + sdv.y));
            float e32 = g3 * __expf(leaky(sv3.z + sdv.z));
            float e33 = g3 * __expf(leaky(sv3.w + sdv.w));
            z0 += e00 + e10 + e20 + e30;
            z1 += e01 + e11 + e21 + e31;
            z2 += e02 + e12 + e22 + e32;
            z3 += e03 + e13 + e23 + e33;
            a0 += e00 * xv0 + e10 * xv1 + e20 * xv2 + e30 * xv3;
            a1 += e01 * xv0 + e11 * xv1 + e21 * xv2 + e31 * xv3;
            a2 += e02 * xv0 + e12 * xv1 + e22 * xv2 + e32 * xv3;
            a3 += e03 * xv0 + e13 * xv1 + e23 * xv2 + e33 * xv3;
        }
        for (; i < degmax; ++i) {
            bool act = i < deg;
            int src = act ? eidx[beg + i] : n;
            float4 sv = *(const float4*)(s1 + src * 8);
            float g = act ? 1.f : 0.f;
            float e0 = g * __expf(leaky(sv.x + sdv.x));
            float e1 = g * __expf(leaky(sv.y + sdv.y));
            float e2 = g * __expf(leaky(sv.z + sdv.z));
            float e3 = g * __expf(leaky(sv.w + sdv.w));
            float xv = (act && c < 27) ? x[src * 27 + c] : 0.f;
            z0 += e0; z1 += e1; z2 += e2; z3 += e3;
            a0 += e0 * xv; a1 += e1 * xv; a2 += e2 * xv; a3 += e3 * xv;
        }
        float i0 = 1.f / (z0 + EPS), i1 = 1.f / (z1 + EPS);
        float i2 = 1.f / (z2 + EPS), i3 = 1.f / (z3 + EPS);
        LDSx[0 * 512 + m * 32 + c] = f2bf(a0 * i0);
        LDSx[1 * 512 + m * 32 + c] = f2bf(a1 * i1);
        LDSx[2 * 512 + m * 32 + c] = f2bf(a2 * i2);
        LDSx[3 * 512 + m * 32 + c] = f2bf(a3 * i3);
    }
    __syncthreads();

    int lane16 = l & 15, quad = l >> 4;
    // Phase B: expand head w: [16x32] @ [32x64] -> elu -> O
    {
        bf16x8 a = *(const bf16x8*)&LDSx[w * 512 + lane16 * 32 + quad * 8];
        f32x4 cacc[4];
        #pragma unroll
        for (int nt = 0; nt < 4; ++nt) {
            bf16x8 b = *(const bf16x8*)&W1b[w * 2048 + (nt * 16 + lane16) * 32 + quad * 8];
            cacc[nt] = __builtin_amdgcn_mfma_f32_16x16x32_bf16(a, b, z4, 0, 0, 0);
        }
        #pragma unroll
        for (int nt = 0; nt < 4; ++nt) {
            int col = w * 64 + nt * 16 + lane16;
            float bb = b1[col];
            #pragma unroll
            for (int r2 = 0; r2 < 4; ++r2) {
                float v = cacc[nt][r2] + bb;
                v = v > 0.f ? v : __expf(v) - 1.f;
                O[(quad * 4 + r2) * 264 + col] = f2bf(v);
            }
        }
    }
    __syncthreads();

    // Phase C: gemm2, wave w -> h2 col-tiles {2w, 2w+1}
    f32x4 acc2[2];
    acc2[0] = z4; acc2[1] = z4;
    for (int k0 = 0; k0 < 256; k0 += 32) {
        bf16x8 a2 = *(const bf16x8*)&O[lane16 * 264 + k0 + quad * 8];
        #pragma unroll
        for (int j = 0; j < 2; ++j) {
            int ct = 2 * w + j;
            bf16x8 b2 = *(const bf16x8*)&W2bT[(ct * 16 + lane16) * 256 + k0 + quad * 8];
            acc2[j] = __builtin_amdgcn_mfma_f32_16x16x32_bf16(a2, b2, acc2[j], 0, 0, 0);
        }
    }
    float ps[4] = {0.f, 0.f, 0.f, 0.f}, pd[4] = {0.f, 0.f, 0.f, 0.f};
    #pragma unroll
    for (int j = 0; j < 2; ++j) {
        int col = (2 * w + j) * 16 + lane16;
        float a_s = as2[col], a_d = ad2[col];
        #pragma unroll
        for (int r2 = 0; r2 < 4; ++r2) {
            ps[r2] += acc2[j][r2] * a_s;
            pd[r2] += acc2[j][r2] * a_d;
            h2b[(n0 + quad * 4 + r2) * 128 + col] = f2bf(acc2[j][r2]);
        }
    }
    #pragma unroll
    for (int off = 1; off <= 8; off <<= 1)
        #pragma unroll
        for (int r2 = 0; r2 < 4; ++r2) {
            ps[r2] += __shfl_xor(ps[r2], off);
            pd[r2] += __shfl_xor(pd[r2], off);
        }
    if (lane16 == 0) {
        #pragma unroll
        for (int r2 = 0; r2 < 4; ++r2) {
            P[w][0][quad * 4 + r2] = ps[r2];
            P[w][1][quad * 4 + r2] = pd[r2];
        }
    }
    __syncthreads();
    if (threadIdx.x < 32) {
        int m = threadIdx.x & 15, hd = threadIdx.x >> 4;
        s2[(n0 + m) * 4 + hd]     = P[2 * hd][0][m] + P[2 * hd + 1][0][m];
        s2[(n0 + m) * 4 + 2 + hd] = P[2 * hd][1][m] + P[2 * hd + 1][1][m];
    }
}

// -------- layer-2 aggregate: wave-per-node, no-max softmax, 4x unrolled ----
// (R11 proven version)
__global__ __launch_bounds__(256) void k_agg2_csr(const int* __restrict__ rowptr,
        const int* __restrict__ eidx, const float* __restrict__ s2,
        const short* __restrict__ h2b, const float* __restrict__ b2,
        const float* __restrict__ Wfc, const float* __restrict__ bfc,
        float* __restrict__ out) {
    int wave = threadIdx.x >> 6;
    int l = threadIdx.x & 63;
    int n = blockIdx.x * 4 + wave;           // grid 12500 -> exact
    int beg = rowptr[n];
    int deg = rowptr[n + 1] - beg;
    int h = l >> 5;
    float sd = s2[n * 4 + 2 + h];
    float2 acc = make_float2(0.f, 0.f);
    float z = 0.f;
    int i = 0;
    for (; i + 4 <= deg; i += 4) {
        int a0 = eidx[beg + i], a1 = eidx[beg + i + 1];
        int a2 = eidx[beg + i + 2], a3 = eidx[beg + i + 3];
        float e0 = __expf(leaky(s2[a0 * 4 + h] + sd));
        float e1 = __expf(leaky(s2[a1 * 4 + h] + sd));
        float e2 = __expf(leaky(s2[a2 * 4 + h] + sd));
        float e3 = __expf(leaky(s2[a3 * 4 + h] + sd));
        unsigned v0 = *(const unsigned*)(h2b + a0 * 128 + l * 2);
        unsigned v1 = *(const unsigned*)(h2b + a1 * 128 + l * 2);
        unsigned v2 = *(const unsigned*)(h2b + a2 * 128 + l * 2);
        unsigned v3 = *(const unsigned*)(h2b + a3 * 128 + l * 2);
        z += e0 + e1 + e2 + e3;
        acc.x += e0 * bflo(v0) + e1 * bflo(v1) + e2 * bflo(v2) + e3 * bflo(v3);
        acc.y += e0 * bfhi(v0) + e1 * bfhi(v1) + e2 * bfhi(v2) + e3 * bfhi(v3);
    }
    for (; i < deg; ++i) {
        int a0 = eidx[beg + i];
        float e0 = __expf(leaky(s2[a0 * 4 + h] + sd));
        unsigned v0 = *(const unsigned*)(h2b + a0 * 128 + l * 2);
        z += e0;
        acc.x += e0 * bflo(v0); acc.y += e0 * bfhi(v0);
    }
    float inv = 1.f / (z + EPS);
    float v0 = acc.x * inv + b2[l * 2];
    float v1 = acc.y * inv + b2[l * 2 + 1];
    v0 = v0 > 0.f ? v0 : __expf(v0) - 1.f;
    v1 = v1 > 0.f ? v1 : __expf(v1) - 1.f;
    float p = v0 * Wfc[l * 2] + v1 * Wfc[l * 2 + 1];
    #pragma unroll
    for (int off = 1; off <= 32; off <<= 1) p += __shfl_xor(p, off);
    if (l == 0) out[n] = 1.f / (1.f + __expf(-(p + bfc[0])));
}

extern "C" void kernel_launch(void* const* d_in, const int* in_sizes, int n_in,
                              void* d_out, int out_size, void* d_ws, size_t ws_size,
                              hipStream_t stream) {
    const float* x   = (const float*)d_in[0];
    const int*   ei  = (const int*)d_in[1];
    const float* W1  = (const float*)d_in[2];
    const float* as1 = (const float*)d_in[3];
    const float* ad1 = (const float*)d_in[4];
    const float* b1  = (const float*)d_in[5];
    const float* W2  = (const float*)d_in[6];
    const float* as2 = (const float*)d_in[7];
    const float* ad2 = (const float*)d_in[8];
    const float* b2  = (const float*)d_in[9];
    const float* Wfc = (const float*)d_in[10];
    const float* bfc = (const float*)d_in[11];
    float* out = (float*)d_out;

    float* f = (float*)d_ws;
    short* h2b   = (short*)f;                    // N*128 bf16
    float* s1    = f + 3200000;                  // N*8
    float* s2    = f + 3600000;                  // N*4
    float* wsv   = f + 3800000;                  // 27*8
    int*   rowptr= (int*)(f + 3810000);          // N+1
    int*   cursor= (int*)(f + 3870000);          // N
    int*   deg   = (int*)(f + 3930000);          // N
    int*   eidx  = (int*)(f + 3990000);          // E_TOT
    int*   bsum  = (int*)(f + 4340000);          // 256
    int*   bofs  = (int*)(f + 4341000);          // 256
    short* W1b   = (short*)(f + 4342000);        // 4*64*32 bf16
    short* W2bT  = (short*)(f + 4350000);        // 128*256 bf16

    // one cooperative launch: CSR build + weight prep + s1
    void* args[] = {(void*)&ei, (void*)&x, (void*)&W1, (void*)&as1,
                    (void*)&ad1, (void*)&W2, (void*)&deg, (void*)&rowptr,
                    (void*)&cursor, (void*)&eidx, (void*)&wsv, (void*)&W1b,
                    (void*)&W2bT, (void*)&s1, (void*)&bsum, (void*)&bofs};
    hipLaunchCooperativeKernel((void*)k_csr_prep, dim3(SCAN_BLOCKS), dim3(256),
                               args, 0, stream);

    // fused: layer-1 aggregation (x-space) + expand + GEMM2 -> h2b, s2
    k_fused1<<<3125, 256, 0, stream>>>(rowptr, eidx, x, s1, W1b, W2bT, b1,
                                       as2, ad2, h2b, s2);

    // layer-2 aggregation + final FC + sigmoid
    k_agg2_csr<<<12500, 256, 0, stream>>>(rowptr, eidx, s2, h2b, b2, Wfc, bfc, out);
}

// Round 15
// 226.639 us; speedup vs baseline: 1.7938x; 1.7938x over previous
//
#include <hip/hip_runtime.h>
#include <math.h>

#define N_NODES 50000
#define E_EDGES 300000
#define E_TOT   350000   // E + N self-loops
#define NEG 0.2f
#define EPS 1e-16f
#define SCAN_BLOCKS 196  // 196*256 = 50176 >= 50000

typedef __attribute__((ext_vector_type(8))) short bf16x8;
typedef __attribute__((ext_vector_type(4))) float f32x4;

__device__ __forceinline__ float leaky(float x) { return x > 0.f ? x : NEG * x; }
// fp32 -> bf16 (RNE, finite inputs)
__device__ __forceinline__ short f2bf(float v) {
    unsigned u = __float_as_uint(v);
    u += 0x7fffu + ((u >> 16) & 1u);
    return (short)(u >> 16);
}
__device__ __forceinline__ float bflo(unsigned u) { return __uint_as_float(u << 16); }
__device__ __forceinline__ float bfhi(unsigned u) { return __uint_as_float(u & 0xffff0000u); }

// ---------------- CSR construction ----------------

__global__ __launch_bounds__(256) void k_hist(const int* __restrict__ ei,
        int* __restrict__ deg) {
    int e = blockIdx.x * 256 + threadIdx.x;
    if (e >= E_TOT) return;
    int d = (e < E_EDGES) ? ei[E_EDGES + e] : (e - E_EDGES);
    atomicAdd(&deg[d], 1);
}

__global__ __launch_bounds__(256) void k_blocksum(const int* __restrict__ deg,
        int* __restrict__ bsum) {
    int t = threadIdx.x;
    int idx = blockIdx.x * 256 + t;
    int v = (idx < N_NODES) ? deg[idx] : 0;
    #pragma unroll
    for (int off = 32; off > 0; off >>= 1) v += __shfl_down(v, off);
    __shared__ int ws[4];
    if ((t & 63) == 0) ws[t >> 6] = v;
    __syncthreads();
    if (t == 0) bsum[blockIdx.x] = ws[0] + ws[1] + ws[2] + ws[3];
}

// rowptr with inlined scan of block sums (every block rescans bsum in LDS)
__global__ __launch_bounds__(256) void k_rowptr(const int* __restrict__ deg,
        const int* __restrict__ bsum, int* __restrict__ rowptr,
        int* __restrict__ cursor) {
    __shared__ int sb[256];
    __shared__ int sh[256];
    int t = threadIdx.x;
    sb[t] = (t < SCAN_BLOCKS) ? bsum[t] : 0;
    __syncthreads();
    for (int s = 1; s < 256; s <<= 1) {
        int v = (t >= s) ? sb[t - s] : 0;
        __syncthreads();
        sb[t] += v;
        __syncthreads();
    }
    int bofs = (blockIdx.x == 0) ? 0 : sb[blockIdx.x - 1];
    int idx = blockIdx.x * 256 + t;
    int v = (idx < N_NODES) ? deg[idx] : 0;
    sh[t] = v;
    __syncthreads();
    for (int s = 1; s < 256; s <<= 1) {
        int u = (t >= s) ? sh[t - s] : 0;
        __syncthreads();
        sh[t] += u;
        __syncthreads();
    }
    int excl = sh[t] - v + bofs;
    if (idx < N_NODES) { rowptr[idx] = excl; cursor[idx] = excl; }
    if (idx == N_NODES) rowptr[N_NODES] = E_TOT;
}

__global__ __launch_bounds__(256) void k_scatter(const int* __restrict__ ei,
        int* __restrict__ cursor, int* __restrict__ eidx) {
    int e = blockIdx.x * 256 + threadIdx.x;
    if (e >= E_TOT) return;
    int s = (e < E_EDGES) ? ei[e] : (e - E_EDGES);
    int d = (e < E_EDGES) ? ei[E_EDGES + e] : (e - E_EDGES);
    int pos = atomicAdd(&cursor[d], 1);
    eidx[pos] = s;
}

// ---------------- s1 GEMV + weight prep (wsv recomputed per block in LDS) ----

__global__ __launch_bounds__(256) void k_s1prep(const float* __restrict__ x,
        const float* __restrict__ W1, const float* __restrict__ as1,
        const float* __restrict__ ad1, const float* __restrict__ W2,
        float* __restrict__ s1, short* __restrict__ W1b,
        short* __restrict__ W2bT) {
    __shared__ float wsv[216];
    int t = threadIdx.x;
    if (t < 216) {                               // wsv[k][j] = W1 row . a
        int k = t >> 3, j = t & 7;
        const float* av = (j < 4) ? (as1 + j * 64) : (ad1 + (j - 4) * 64);
        const float* wr = W1 + k * 256 + ((j & 3) * 64);
        float s = 0.f;
        for (int d = 0; d < 64; ++d) s += wr[d] * av[d];
        wsv[t] = s;
    }
    int b = blockIdx.x;
    if (b < 128) {                               // weight prep slices
        int i = b * 256 + t;                     // 0..32767
        int col = i >> 8, k = i & 255;
        W2bT[i] = f2bf(W2[k * 128 + col]);       // W2bT[col][k]
        if (i < 8192) {
            int h = i >> 11, c2 = (i >> 5) & 63, k2 = i & 31;
            W1b[i] = f2bf(k2 < 27 ? W1[k2 * 256 + h * 64 + c2] : 0.f);
        }
    }
    __syncthreads();
    int idx = blockIdx.x * 256 + t;              // grid 1563
    if (idx < N_NODES * 8) {
        int n = idx >> 3, j = idx & 7;
        float s = 0.f;
        #pragma unroll
        for (int k = 0; k < 27; ++k) s += x[n * 27 + k] * wsv[k * 8 + j];
        s1[idx] = s;
    }
}

// ---------------- fused layer-1 agg (x-space) + expand + GEMM2 ----------------
// (R11 proven version) Block = 16 nodes; Phase A gather (4x unroll), Phase B
// expand head w via MFMA + elu -> LDS, Phase C GEMM2 (K=256) + s2.
__global__ __launch_bounds__(256) void k_fused1(const int* __restrict__ rowptr,
        const int* __restrict__ eidx, const float* __restrict__ x,
        const float* __restrict__ s1, const short* __restrict__ W1b,
        const short* __restrict__ W2bT, const float* __restrict__ b1,
        const float* __restrict__ as2, const float* __restrict__ ad2,
        short* __restrict__ h2b, float* __restrict__ s2) {
    __shared__ short LDSx[4 * 16 * 32];          // [head][m][k] bf16
    __shared__ short O[16 * 264];                // out1' [m][col], padded stride
    __shared__ float P[4][2][16];                // s2 partials [wave][ps/pd][m]
    int w = threadIdx.x >> 6, l = threadIdx.x & 63;
    int n0 = blockIdx.x * 16;                    // grid 3125 -> 50000 exact
    int h5 = l >> 5, c = l & 31;                 // half-wave, channel slot
    f32x4 z4 = {0.f, 0.f, 0.f, 0.f};

    for (int r = 0; r < 2; ++r) {
        int m = w * 4 + r * 2 + h5;
        int n = n0 + m;
        int beg = rowptr[n];
        int deg = rowptr[n + 1] - beg;
        int degmax = max(deg, __shfl_xor(deg, 32));
        float4 sdv = *(const float4*)(s1 + n * 8 + 4);
        float a0 = 0.f, a1 = 0.f, a2 = 0.f, a3 = 0.f;
        float z0 = 0.f, z1 = 0.f, z2 = 0.f, z3 = 0.f;
        int i = 0;
        for (; i + 4 <= degmax; i += 4) {
            bool c0 = (i + 0) < deg, c1 = (i + 1) < deg;
            bool c2 = (i + 2) < deg, c3 = (i + 3) < deg;
            int s0 = c0 ? eidx[beg + i + 0] : n;
            int s1i = c1 ? eidx[beg + i + 1] : n;
            int s2i = c2 ? eidx[beg + i + 2] : n;
            int s3 = c3 ? eidx[beg + i + 3] : n;
            float4 sv0 = *(const float4*)(s1 + s0 * 8);
            float4 sv1 = *(const float4*)(s1 + s1i * 8);
            float4 sv2 = *(const float4*)(s1 + s2i * 8);
            float4 sv3 = *(const float4*)(s1 + s3 * 8);
            float xv0 = (c0 && c < 27) ? x[s0 * 27 + c] : 0.f;
            float xv1 = (c1 && c < 27) ? x[s1i * 27 + c] : 0.f;
            float xv2 = (c2 && c < 27) ? x[s2i * 27 + c] : 0.f;
            float xv3 = (c3 && c < 27) ? x[s3 * 27 + c] : 0.f;
            float g0 = c0 ? 1.f : 0.f, g1 = c1 ? 1.f : 0.f;
            float g2 = c2 ? 1.f : 0.f, g3 = c3 ? 1.f : 0.f;
            float e00 = g0 * __expf(leaky(sv0.x + sdv.x));
            float e01 = g0 * __expf(leaky(sv0.y + sdv.y));
            float e02 = g0 * __expf(leaky(sv0.z + sdv.z));
            float e03 = g0 * __expf(leaky(sv0.w + sdv.w));
            float e10 = g1 * __expf(leaky(sv1.x + sdv.x));
            float e11 = g1 * __expf(leaky(sv1.y + sdv.y));
            float e12 = g1 * __expf(leaky(sv1.z + sdv.z));
            float e13 = g1 * __expf(leaky(sv1.w + sdv.w));
            float e20 = g2 * __expf(leaky(sv2.x + sdv.x));
            float e21 = g2 * __expf(leaky(sv2.y + sdv.y));
            float e22 = g2 * __expf(leaky(sv2.z + sdv.z));
            float e23 = g2 * __expf(leaky(sv2.w + sdv.w));
            float e30 = g3 * __expf(leaky(sv3.x + sdv.x));
            float e31 = g3 * __expf(leaky(sv3.y + sdv.y));
            float e32 = g3 * __expf(leaky(sv3.z + sdv.z));
            float e33 = g3 * __expf(leaky(sv3.w + sdv.w));
            z0 += e00 + e10 + e20 + e30;
            z1 += e01 + e11 + e21 + e31;
            z2 += e02 + e12 + e22 + e32;
            z3 += e03 + e13 + e23 + e33;
            a0 += e00 * xv0 + e10 * xv1 + e20 * xv2 + e30 * xv3;
            a1 += e01 * xv0 + e11 * xv1 + e21 * xv2 + e31 * xv3;
            a2 += e02 * xv0 + e12 * xv1 + e22 * xv2 + e32 * xv3;
            a3 += e03 * xv0 + e13 * xv1 + e23 * xv2 + e33 * xv3;
        }
        for (; i < degmax; ++i) {
            bool act = i < deg;
            int src = act ? eidx[beg + i] : n;
            float4 sv = *(const float4*)(s1 + src * 8);
            float g = act ? 1.f : 0.f;
            float e0 = g * __expf(leaky(sv.x + sdv.x));
            float e1 = g * __expf(leaky(sv.y + sdv.y));
            float e2 = g * __expf(leaky(sv.z + sdv.z));
            float e3 = g * __expf(leaky(sv.w + sdv.w));
            float xv = (act && c < 27) ? x[src * 27 + c] : 0.f;
            z0 += e0; z1 += e1; z2 += e2; z3 += e3;
            a0 += e0 * xv; a1 += e1 * xv; a2 += e2 * xv; a3 += e3 * xv;
        }
        float i0 = 1.f / (z0 + EPS), i1 = 1.f / (z1 + EPS);
        float i2 = 1.f / (z2 + EPS), i3 = 1.f / (z3 + EPS);
        LDSx[0 * 512 + m * 32 + c] = f2bf(a0 * i0);
        LDSx[1 * 512 + m * 32 + c] = f2bf(a1 * i1);
        LDSx[2 * 512 + m * 32 + c] = f2bf(a2 * i2);
        LDSx[3 * 512 + m * 32 + c] = f2bf(a3 * i3);
    }
    __syncthreads();

    int lane16 = l & 15, quad = l >> 4;
    // Phase B: expand head w: [16x32] @ [32x64] -> elu -> O
    {
        bf16x8 a = *(const bf16x8*)&LDSx[w * 512 + lane16 * 32 + quad * 8];
        f32x4 cacc[4];
        #pragma unroll
        for (int nt = 0; nt < 4; ++nt) {
            bf16x8 b = *(const bf16x8*)&W1b[w * 2048 + (nt * 16 + lane16) * 32 + quad * 8];
            cacc[nt] = __builtin_amdgcn_mfma_f32_16x16x32_bf16(a, b, z4, 0, 0, 0);
        }
        #pragma unroll
        for (int nt = 0; nt < 4; ++nt) {
            int col = w * 64 + nt * 16 + lane16;
            float bb = b1[col];
            #pragma unroll
            for (int r2 = 0; r2 < 4; ++r2) {
                float v = cacc[nt][r2] + bb;
                v = v > 0.f ? v : __expf(v) - 1.f;
                O[(quad * 4 + r2) * 264 + col] = f2bf(v);
            }
        }
    }
    __syncthreads();

    // Phase C: gemm2, wave w -> h2 col-tiles {2w, 2w+1}
    f32x4 acc2[2];
    acc2[0] = z4; acc2[1] = z4;
    for (int k0 = 0; k0 < 256; k0 += 32) {
        bf16x8 a2 = *(const bf16x8*)&O[lane16 * 264 + k0 + quad * 8];
        #pragma unroll
        for (int j = 0; j < 2; ++j) {
            int ct = 2 * w + j;
            bf16x8 b2 = *(const bf16x8*)&W2bT[(ct * 16 + lane16) * 256 + k0 + quad * 8];
            acc2[j] = __builtin_amdgcn_mfma_f32_16x16x32_bf16(a2, b2, acc2[j], 0, 0, 0);
        }
    }
    float ps[4] = {0.f, 0.f, 0.f, 0.f}, pd[4] = {0.f, 0.f, 0.f, 0.f};
    #pragma unroll
    for (int j = 0; j < 2; ++j) {
        int col = (2 * w + j) * 16 + lane16;
        float a_s = as2[col], a_d = ad2[col];
        #pragma unroll
        for (int r2 = 0; r2 < 4; ++r2) {
            ps[r2] += acc2[j][r2] * a_s;
            pd[r2] += acc2[j][r2] * a_d;
            h2b[(n0 + quad * 4 + r2) * 128 + col] = f2bf(acc2[j][r2]);
        }
    }
    #pragma unroll
    for (int off = 1; off <= 8; off <<= 1)
        #pragma unroll
        for (int r2 = 0; r2 < 4; ++r2) {
            ps[r2] += __shfl_xor(ps[r2], off);
            pd[r2] += __shfl_xor(pd[r2], off);
        }
    if (lane16 == 0) {
        #pragma unroll
        for (int r2 = 0; r2 < 4; ++r2) {
            P[w][0][quad * 4 + r2] = ps[r2];
            P[w][1][quad * 4 + r2] = pd[r2];
        }
    }
    __syncthreads();
    if (threadIdx.x < 32) {
        int m = threadIdx.x & 15, hd = threadIdx.x >> 4;
        s2[(n0 + m) * 4 + hd]     = P[2 * hd][0][m] + P[2 * hd + 1][0][m];
        s2[(n0 + m) * 4 + 2 + hd] = P[2 * hd][1][m] + P[2 * hd + 1][1][m];
    }
}

// -------- layer-2 aggregate: wave-per-node, masked 8-wide gather burst ----

__global__ __launch_bounds__(256) void k_agg2_csr(const int* __restrict__ rowptr,
        const int* __restrict__ eidx, const float* __restrict__ s2,
        const short* __restrict__ h2b, const float* __restrict__ b2,
        const float* __restrict__ Wfc, const float* __restrict__ bfc,
        float* __restrict__ out) {
    int wave = threadIdx.x >> 6;
    int l = threadIdx.x & 63;
    int n = blockIdx.x * 4 + wave;           // grid 12500 -> exact
    int beg = rowptr[n];
    int deg = rowptr[n + 1] - beg;
    int h = l >> 5;
    float sd = s2[n * 4 + 2 + h];
    float2 acc = make_float2(0.f, 0.f);
    float z = 0.f;
    int last = beg + deg - 1;
    for (int i = 0; i < deg; i += 8) {
        int p0 = min(beg + i + 0, last), p1 = min(beg + i + 1, last);
        int p2 = min(beg + i + 2, last), p3 = min(beg + i + 3, last);
        int p4 = min(beg + i + 4, last), p5 = min(beg + i + 5, last);
        int p6 = min(beg + i + 6, last), p7 = min(beg + i + 7, last);
        int a0 = eidx[p0], a1 = eidx[p1], a2 = eidx[p2], a3 = eidx[p3];
        int a4 = eidx[p4], a5 = eidx[p5], a6 = eidx[p6], a7 = eidx[p7];
        float e0 = (i + 0 < deg) ? __expf(leaky(s2[a0 * 4 + h] + sd)) : 0.f;
        float e1 = (i + 1 < deg) ? __expf(leaky(s2[a1 * 4 + h] + sd)) : 0.f;
        float e2 = (i + 2 < deg) ? __expf(leaky(s2[a2 * 4 + h] + sd)) : 0.f;
        float e3 = (i + 3 < deg) ? __expf(leaky(s2[a3 * 4 + h] + sd)) : 0.f;
        float e4 = (i + 4 < deg) ? __expf(leaky(s2[a4 * 4 + h] + sd)) : 0.f;
        float e5 = (i + 5 < deg) ? __expf(leaky(s2[a5 * 4 + h] + sd)) : 0.f;
        float e6 = (i + 6 < deg) ? __expf(leaky(s2[a6 * 4 + h] + sd)) : 0.f;
        float e7 = (i + 7 < deg) ? __expf(leaky(s2[a7 * 4 + h] + sd)) : 0.f;
        unsigned v0 = *(const unsigned*)(h2b + a0 * 128 + l * 2);
        unsigned v1 = *(const unsigned*)(h2b + a1 * 128 + l * 2);
        unsigned v2 = *(const unsigned*)(h2b + a2 * 128 + l * 2);
        unsigned v3 = *(const unsigned*)(h2b + a3 * 128 + l * 2);
        unsigned v4 = *(const unsigned*)(h2b + a4 * 128 + l * 2);
        unsigned v5 = *(const unsigned*)(h2b + a5 * 128 + l * 2);
        unsigned v6 = *(const unsigned*)(h2b + a6 * 128 + l * 2);
        unsigned v7 = *(const unsigned*)(h2b + a7 * 128 + l * 2);
        z += ((e0 + e1) + (e2 + e3)) + ((e4 + e5) + (e6 + e7));
        acc.x += e0 * bflo(v0) + e1 * bflo(v1) + e2 * bflo(v2) + e3 * bflo(v3)
               + e4 * bflo(v4) + e5 * bflo(v5) + e6 * bflo(v6) + e7 * bflo(v7);
        acc.y += e0 * bfhi(v0) + e1 * bfhi(v1) + e2 * bfhi(v2) + e3 * bfhi(v3)
               + e4 * bfhi(v4) + e5 * bfhi(v5) + e6 * bfhi(v6) + e7 * bfhi(v7);
    }
    float inv = 1.f / (z + EPS);
    float v0 = acc.x * inv + b2[l * 2];
    float v1 = acc.y * inv + b2[l * 2 + 1];
    v0 = v0 > 0.f ? v0 : __expf(v0) - 1.f;
    v1 = v1 > 0.f ? v1 : __expf(v1) - 1.f;
    float p = v0 * Wfc[l * 2] + v1 * Wfc[l * 2 + 1];
    #pragma unroll
    for (int off = 1; off <= 32; off <<= 1) p += __shfl_xor(p, off);
    if (l == 0) out[n] = 1.f / (1.f + __expf(-(p + bfc[0])));
}

extern "C" void kernel_launch(void* const* d_in, const int* in_sizes, int n_in,
                              void* d_out, int out_size, void* d_ws, size_t ws_size,
                              hipStream_t stream) {
    const float* x   = (const float*)d_in[0];
    const int*   ei  = (const int*)d_in[1];
    const float* W1  = (const float*)d_in[2];
    const float* as1 = (const float*)d_in[3];
    const float* ad1 = (const float*)d_in[4];
    const float* b1  = (const float*)d_in[5];
    const float* W2  = (const float*)d_in[6];
    const float* as2 = (const float*)d_in[7];
    const float* ad2 = (const float*)d_in[8];
    const float* b2  = (const float*)d_in[9];
    const float* Wfc = (const float*)d_in[10];
    const float* bfc = (const float*)d_in[11];
    float* out = (float*)d_out;

    float* f = (float*)d_ws;
    short* h2b   = (short*)f;                    // N*128 bf16
    float* s1    = f + 3200000;                  // N*8
    float* s2    = f + 3600000;                  // N*4
    int*   rowptr= (int*)(f + 3810000);          // N+1
    int*   cursor= (int*)(f + 3870000);          // N
    int*   deg   = (int*)(f + 3930000);          // N
    int*   eidx  = (int*)(f + 3990000);          // E_TOT
    int*   bsum  = (int*)(f + 4340000);          // 256
    short* W1b   = (short*)(f + 4342000);        // 4*64*32 bf16
    short* W2bT  = (short*)(f + 4350000);        // 128*256 bf16

    // CSR build (full-occupancy small kernels)
    hipMemsetAsync(deg, 0, (size_t)N_NODES * 4, stream);
    k_hist<<<(E_TOT + 255) / 256, 256, 0, stream>>>(ei, deg);
    k_blocksum<<<SCAN_BLOCKS, 256, 0, stream>>>(deg, bsum);
    k_rowptr<<<SCAN_BLOCKS, 256, 0, stream>>>(deg, bsum, rowptr, cursor);
    k_scatter<<<(E_TOT + 255) / 256, 256, 0, stream>>>(ei, cursor, eidx);

    // s1 GEMV + weight prep (one launch)
    k_s1prep<<<1563, 256, 0, stream>>>(x, W1, as1, ad1, W2, s1, W1b, W2bT);

    // fused: layer-1 aggregation (x-space) + expand + GEMM2 -> h2b, s2
    k_fused1<<<3125, 256, 0, stream>>>(rowptr, eidx, x, s1, W1b, W2bT, b1,
                                       as2, ad2, h2b, s2);

    // layer-2 aggregation + final FC + sigmoid
    k_agg2_csr<<<12500, 256, 0, stream>>>(rowptr, eidx, s2, h2b, b2, Wfc, bfc, out);
}

// Round 16
// 198.319 us; speedup vs baseline: 2.0500x; 1.1428x over previous
//
#include <hip/hip_runtime.h>
#include <math.h>

#define N_NODES 50000
#define E_EDGES 300000
#define E_TOT   350000   // E + N self-loops
#define NEG 0.2f
#define EPS 1e-16f
#define SCAN_BLOCKS 196  // 196*256 = 50176 >= 50000

typedef __attribute__((ext_vector_type(8))) short bf16x8;
typedef __attribute__((ext_vector_type(4))) float f32x4;

__device__ __forceinline__ float leaky(float x) { return x > 0.f ? x : NEG * x; }
// fp32 -> bf16 (RNE, finite inputs)
__device__ __forceinline__ short f2bf(float v) {
    unsigned u = __float_as_uint(v);
    u += 0x7fffu + ((u >> 16) & 1u);
    return (short)(u >> 16);
}
__device__ __forceinline__ float bflo(unsigned u) { return __uint_as_float(u << 16); }
__device__ __forceinline__ float bfhi(unsigned u) { return __uint_as_float(u & 0xffff0000u); }

// ---------------- CSR construction (R11 proven) ----------------

__global__ __launch_bounds__(256) void k_hist(const int* __restrict__ ei,
        int* __restrict__ deg) {
    int e = blockIdx.x * 256 + threadIdx.x;
    if (e >= E_TOT) return;
    int d = (e < E_EDGES) ? ei[E_EDGES + e] : (e - E_EDGES);
    atomicAdd(&deg[d], 1);
}

__global__ __launch_bounds__(256) void k_blocksum(const int* __restrict__ deg,
        int* __restrict__ bsum) {
    int t = threadIdx.x;
    int idx = blockIdx.x * 256 + t;
    int v = (idx < N_NODES) ? deg[idx] : 0;
    #pragma unroll
    for (int off = 32; off > 0; off >>= 1) v += __shfl_down(v, off);
    __shared__ int ws[4];
    if ((t & 63) == 0) ws[t >> 6] = v;
    __syncthreads();
    if (t == 0) bsum[blockIdx.x] = ws[0] + ws[1] + ws[2] + ws[3];
}

__global__ __launch_bounds__(256) void k_scanb(const int* __restrict__ bsum,
        int* __restrict__ bofs) {
    __shared__ int sh[256];
    int t = threadIdx.x;
    sh[t] = (t < SCAN_BLOCKS) ? bsum[t] : 0;
    __syncthreads();
    for (int s = 1; s < 256; s <<= 1) {
        int v = (t >= s) ? sh[t - s] : 0;
        __syncthreads();
        sh[t] += v;
        __syncthreads();
    }
    bofs[t] = (t == 0) ? 0 : sh[t - 1];
}

__global__ __launch_bounds__(256) void k_rowptr(const int* __restrict__ deg,
        const int* __restrict__ bofs, int* __restrict__ rowptr,
        int* __restrict__ cursor) {
    __shared__ int sh[256];
    int t = threadIdx.x;
    int idx = blockIdx.x * 256 + t;
    int v = (idx < N_NODES) ? deg[idx] : 0;
    sh[t] = v;
    __syncthreads();
    for (int s = 1; s < 256; s <<= 1) {
        int u = (t >= s) ? sh[t - s] : 0;
        __syncthreads();
        sh[t] += u;
        __syncthreads();
    }
    int excl = sh[t] - v + bofs[blockIdx.x];
    if (idx < N_NODES) { rowptr[idx] = excl; cursor[idx] = excl; }
    if (idx == N_NODES) rowptr[N_NODES] = E_TOT;
}

__global__ __launch_bounds__(256) void k_scatter(const int* __restrict__ ei,
        int* __restrict__ cursor, int* __restrict__ eidx) {
    int e = blockIdx.x * 256 + threadIdx.x;
    if (e >= E_TOT) return;
    int s = (e < E_EDGES) ? ei[e] : (e - E_EDGES);
    int d = (e < E_EDGES) ? ei[E_EDGES + e] : (e - E_EDGES);
    int pos = atomicAdd(&cursor[d], 1);
    eidx[pos] = s;
}

// ---------------- prep: wsv = W1·a vectors, W1b (padded B^T), W2bT ----------

__global__ __launch_bounds__(256) void k_prep(const float* __restrict__ W1,
        const float* __restrict__ as1, const float* __restrict__ ad1,
        const float* __restrict__ W2, float* __restrict__ wsv,
        short* __restrict__ W1b, short* __restrict__ W2bT) {
    int t = blockIdx.x * 256 + threadIdx.x;      // grid 128 -> 32768 threads
    {
        int col = t >> 8, k = t & 255;
        W2bT[t] = f2bf(W2[k * 128 + col]);
    }
    if (t < 8192) {
        int h = t >> 11, col = (t >> 5) & 63, k = t & 31;
        W1b[t] = f2bf(k < 27 ? W1[k * 256 + h * 64 + col] : 0.f);
    }
    if (t < 216) {
        int k = t >> 3, j = t & 7;
        const float* av = (j < 4) ? (as1 + j * 64) : (ad1 + (j - 4) * 64);
        const float* wr = W1 + k * 256 + ((j & 3) * 64);
        float s = 0.f;
        for (int d = 0; d < 64; ++d) s += wr[d] * av[d];
        wsv[k * 8 + j] = s;
    }
}

// s1[n][0..3]=src half-scores, [4..7]=dst — direct from x via wsv (27->8 GEMV)
__global__ __launch_bounds__(256) void k_s1(const float* __restrict__ x,
        const float* __restrict__ wsv, float* __restrict__ s1) {
    int idx = blockIdx.x * 256 + threadIdx.x;    // grid 1563
    if (idx >= N_NODES * 8) return;
    int n = idx >> 3, j = idx & 7;
    float s = 0.f;
    #pragma unroll
    for (int k = 0; k < 27; ++k) s += x[n * 27 + k] * wsv[k * 8 + j];
    s1[idx] = s;
}

// ---------------- fused layer-1 agg (x-space) + expand + GEMM2 ----------------
// Phase A: QUARTER-wave (16 lanes) per node, ONE round; lane q covers channels
// {q, q+16}; deg uniform per group -> no masking. Phase B/C unchanged (R11).
__global__ __launch_bounds__(256) void k_fused1(const int* __restrict__ rowptr,
        const int* __restrict__ eidx, const float* __restrict__ x,
        const float* __restrict__ s1, const short* __restrict__ W1b,
        const short* __restrict__ W2bT, const float* __restrict__ b1,
        const float* __restrict__ as2, const float* __restrict__ ad2,
        short* __restrict__ h2b, float* __restrict__ s2) {
    __shared__ short LDSx[4 * 16 * 32];          // [head][m][k] bf16
    __shared__ short O[16 * 264];                // out1' [m][col], padded stride
    __shared__ float P[4][2][16];                // s2 partials [wave][ps/pd][m]
    int w = threadIdx.x >> 6, l = threadIdx.x & 63;
    int n0 = blockIdx.x * 16;                    // grid 3125 -> 50000 exact
    f32x4 z4 = {0.f, 0.f, 0.f, 0.f};

    // Phase A: group g (16 lanes) aggregates node n0+g
    {
        int g = threadIdx.x >> 4;                // 0..15
        int q = threadIdx.x & 15;                // lane in group = channel q
        int n = n0 + g;
        int beg = rowptr[n];
        int deg = rowptr[n + 1] - beg;
        float4 sdv = *(const float4*)(s1 + n * 8 + 4);
        bool cx1 = (q + 16) < 27;                // channel q+16 valid
        float a0 = 0.f, a1 = 0.f, a2 = 0.f, a3 = 0.f;   // channel q
        float b0 = 0.f, b1v = 0.f, b2v = 0.f, b3 = 0.f; // channel q+16
        float z0 = 0.f, z1 = 0.f, z2 = 0.f, z3 = 0.f;
        int i = 0;
        for (; i + 4 <= deg; i += 4) {
            int s0 = eidx[beg + i + 0];
            int s1i = eidx[beg + i + 1];
            int s2i = eidx[beg + i + 2];
            int s3 = eidx[beg + i + 3];
            float4 sv0 = *(const float4*)(s1 + s0 * 8);
            float4 sv1 = *(const float4*)(s1 + s1i * 8);
            float4 sv2 = *(const float4*)(s1 + s2i * 8);
            float4 sv3 = *(const float4*)(s1 + s3 * 8);
            float xa0 = x[s0 * 27 + q],  xb0 = cx1 ? x[s0 * 27 + q + 16] : 0.f;
            float xa1 = x[s1i * 27 + q], xb1 = cx1 ? x[s1i * 27 + q + 16] : 0.f;
            float xa2 = x[s2i * 27 + q], xb2 = cx1 ? x[s2i * 27 + q + 16] : 0.f;
            float xa3 = x[s3 * 27 + q],  xb3 = cx1 ? x[s3 * 27 + q + 16] : 0.f;
            float e00 = __expf(leaky(sv0.x + sdv.x));
            float e01 = __expf(leaky(sv0.y + sdv.y));
            float e02 = __expf(leaky(sv0.z + sdv.z));
            float e03 = __expf(leaky(sv0.w + sdv.w));
            float e10 = __expf(leaky(sv1.x + sdv.x));
            float e11 = __expf(leaky(sv1.y + sdv.y));
            float e12 = __expf(leaky(sv1.z + sdv.z));
            float e13 = __expf(leaky(sv1.w + sdv.w));
            float e20 = __expf(leaky(sv2.x + sdv.x));
            float e21 = __expf(leaky(sv2.y + sdv.y));
            float e22 = __expf(leaky(sv2.z + sdv.z));
            float e23 = __expf(leaky(sv2.w + sdv.w));
            float e30 = __expf(leaky(sv3.x + sdv.x));
            float e31 = __expf(leaky(sv3.y + sdv.y));
            float e32 = __expf(leaky(sv3.z + sdv.z));
            float e33 = __expf(leaky(sv3.w + sdv.w));
            z0 += e00 + e10 + e20 + e30;
            z1 += e01 + e11 + e21 + e31;
            z2 += e02 + e12 + e22 + e32;
            z3 += e03 + e13 + e23 + e33;
            a0 += e00 * xa0 + e10 * xa1 + e20 * xa2 + e30 * xa3;
            a1 += e01 * xa0 + e11 * xa1 + e21 * xa2 + e31 * xa3;
            a2 += e02 * xa0 + e12 * xa1 + e22 * xa2 + e32 * xa3;
            a3 += e03 * xa0 + e13 * xa1 + e23 * xa2 + e33 * xa3;
            b0  += e00 * xb0 + e10 * xb1 + e20 * xb2 + e30 * xb3;
            b1v += e01 * xb0 + e11 * xb1 + e21 * xb2 + e31 * xb3;
            b2v += e02 * xb0 + e12 * xb1 + e22 * xb2 + e32 * xb3;
            b3  += e03 * xb0 + e13 * xb1 + e23 * xb2 + e33 * xb3;
        }
        for (; i < deg; ++i) {
            int s0 = eidx[beg + i];
            float4 sv = *(const float4*)(s1 + s0 * 8);
            float xa = x[s0 * 27 + q];
            float xb = cx1 ? x[s0 * 27 + q + 16] : 0.f;
            float e0 = __expf(leaky(sv.x + sdv.x));
            float e1 = __expf(leaky(sv.y + sdv.y));
            float e2 = __expf(leaky(sv.z + sdv.z));
            float e3 = __expf(leaky(sv.w + sdv.w));
            z0 += e0; z1 += e1; z2 += e2; z3 += e3;
            a0 += e0 * xa; a1 += e1 * xa; a2 += e2 * xa; a3 += e3 * xa;
            b0 += e0 * xb; b1v += e1 * xb; b2v += e2 * xb; b3 += e3 * xb;
        }
        float i0 = 1.f / (z0 + EPS), i1 = 1.f / (z1 + EPS);
        float i2 = 1.f / (z2 + EPS), i3 = 1.f / (z3 + EPS);
        LDSx[0 * 512 + g * 32 + q] = f2bf(a0 * i0);
        LDSx[1 * 512 + g * 32 + q] = f2bf(a1 * i1);
        LDSx[2 * 512 + g * 32 + q] = f2bf(a2 * i2);
        LDSx[3 * 512 + g * 32 + q] = f2bf(a3 * i3);
        LDSx[0 * 512 + g * 32 + q + 16] = f2bf(b0 * i0);
        LDSx[1 * 512 + g * 32 + q + 16] = f2bf(b1v * i1);
        LDSx[2 * 512 + g * 32 + q + 16] = f2bf(b2v * i2);
        LDSx[3 * 512 + g * 32 + q + 16] = f2bf(b3 * i3);
    }
    __syncthreads();

    int lane16 = l & 15, quad = l >> 4;
    // Phase B: expand head w: [16x32] @ [32x64] -> elu -> O
    {
        bf16x8 a = *(const bf16x8*)&LDSx[w * 512 + lane16 * 32 + quad * 8];
        f32x4 cacc[4];
        #pragma unroll
        for (int nt = 0; nt < 4; ++nt) {
            bf16x8 b = *(const bf16x8*)&W1b[w * 2048 + (nt * 16 + lane16) * 32 + quad * 8];
            cacc[nt] = __builtin_amdgcn_mfma_f32_16x16x32_bf16(a, b, z4, 0, 0, 0);
        }
        #pragma unroll
        for (int nt = 0; nt < 4; ++nt) {
            int col = w * 64 + nt * 16 + lane16;
            float bb = b1[col];
            #pragma unroll
            for (int r2 = 0; r2 < 4; ++r2) {
                float v = cacc[nt][r2] + bb;
                v = v > 0.f ? v : __expf(v) - 1.f;
                O[(quad * 4 + r2) * 264 + col] = f2bf(v);
            }
        }
    }
    __syncthreads();

    // Phase C: gemm2, wave w -> h2 col-tiles {2w, 2w+1}
    f32x4 acc2[2];
    acc2[0] = z4; acc2[1] = z4;
    for (int k0 = 0; k0 < 256; k0 += 32) {
        bf16x8 a2 = *(const bf16x8*)&O[lane16 * 264 + k0 + quad * 8];
        #pragma unroll
        for (int j = 0; j < 2; ++j) {
            int ct = 2 * w + j;
            bf16x8 b2 = *(const bf16x8*)&W2bT[(ct * 16 + lane16) * 256 + k0 + quad * 8];
            acc2[j] = __builtin_amdgcn_mfma_f32_16x16x32_bf16(a2, b2, acc2[j], 0, 0, 0);
        }
    }
    float ps[4] = {0.f, 0.f, 0.f, 0.f}, pd[4] = {0.f, 0.f, 0.f, 0.f};
    #pragma unroll
    for (int j = 0; j < 2; ++j) {
        int col = (2 * w + j) * 16 + lane16;
        float a_s = as2[col], a_d = ad2[col];
        #pragma unroll
        for (int r2 = 0; r2 < 4; ++r2) {
            ps[r2] += acc2[j][r2] * a_s;
            pd[r2] += acc2[j][r2] * a_d;
            h2b[(n0 + quad * 4 + r2) * 128 + col] = f2bf(acc2[j][r2]);
        }
    }
    #pragma unroll
    for (int off = 1; off <= 8; off <<= 1)
        #pragma unroll
        for (int r2 = 0; r2 < 4; ++r2) {
            ps[r2] += __shfl_xor(ps[r2], off);
            pd[r2] += __shfl_xor(pd[r2], off);
        }
    if (lane16 == 0) {
        #pragma unroll
        for (int r2 = 0; r2 < 4; ++r2) {
            P[w][0][quad * 4 + r2] = ps[r2];
            P[w][1][quad * 4 + r2] = pd[r2];
        }
    }
    __syncthreads();
    if (threadIdx.x < 32) {
        int m = threadIdx.x & 15, hd = threadIdx.x >> 4;
        s2[(n0 + m) * 4 + hd]     = P[2 * hd][0][m] + P[2 * hd + 1][0][m];
        s2[(n0 + m) * 4 + 2 + hd] = P[2 * hd][1][m] + P[2 * hd + 1][1][m];
    }
}

// -------- layer-2 aggregate: wave-per-node, no-max softmax, 4x unrolled ----
// (R11 proven version)
__global__ __launch_bounds__(256) void k_agg2_csr(const int* __restrict__ rowptr,
        const int* __restrict__ eidx, const float* __restrict__ s2,
        const short* __restrict__ h2b, const float* __restrict__ b2,
        const float* __restrict__ Wfc, const float* __restrict__ bfc,
        float* __restrict__ out) {
    int wave = threadIdx.x >> 6;
    int l = threadIdx.x & 63;
    int n = blockIdx.x * 4 + wave;           // grid 12500 -> exact
    int beg = rowptr[n];
    int deg = rowptr[n + 1] - beg;
    int h = l >> 5;
    float sd = s2[n * 4 + 2 + h];
    float2 acc = make_float2(0.f, 0.f);
    float z = 0.f;
    int i = 0;
    for (; i + 4 <= deg; i += 4) {
        int a0 = eidx[beg + i], a1 = eidx[beg + i + 1];
        int a2 = eidx[beg + i + 2], a3 = eidx[beg + i + 3];
        float e0 = __expf(leaky(s2[a0 * 4 + h] + sd));
        float e1 = __expf(leaky(s2[a1 * 4 + h] + sd));
        float e2 = __expf(leaky(s2[a2 * 4 + h] + sd));
        float e3 = __expf(leaky(s2[a3 * 4 + h] + sd));
        unsigned v0 = *(const unsigned*)(h2b + a0 * 128 + l * 2);
        unsigned v1 = *(const unsigned*)(h2b + a1 * 128 + l * 2);
        unsigned v2 = *(const unsigned*)(h2b + a2 * 128 + l * 2);
        unsigned v3 = *(const unsigned*)(h2b + a3 * 128 + l * 2);
        z += e0 + e1 + e2 + e3;
        acc.x += e0 * bflo(v0) + e1 * bflo(v1) + e2 * bflo(v2) + e3 * bflo(v3);
        acc.y += e0 * bfhi(v0) + e1 * bfhi(v1) + e2 * bfhi(v2) + e3 * bfhi(v3);
    }
    for (; i < deg; ++i) {
        int a0 = eidx[beg + i];
        float e0 = __expf(leaky(s2[a0 * 4 + h] + sd));
        unsigned v0 = *(const unsigned*)(h2b + a0 * 128 + l * 2);
        z += e0;
        acc.x += e0 * bflo(v0); acc.y += e0 * bfhi(v0);
    }
    float inv = 1.f / (z + EPS);
    float v0 = acc.x * inv + b2[l * 2];
    float v1 = acc.y * inv + b2[l * 2 + 1];
    v0 = v0 > 0.f ? v0 : __expf(v0) - 1.f;
    v1 = v1 > 0.f ? v1 : __expf(v1) - 1.f;
    float p = v0 * Wfc[l * 2] + v1 * Wfc[l * 2 + 1];
    #pragma unroll
    for (int off = 1; off <= 32; off <<= 1) p += __shfl_xor(p, off);
    if (l == 0) out[n] = 1.f / (1.f + __expf(-(p + bfc[0])));
}

extern "C" void kernel_launch(void* const* d_in, const int* in_sizes, int n_in,
                              void* d_out, int out_size, void* d_ws, size_t ws_size,
                              hipStream_t stream) {
    const float* x   = (const float*)d_in[0];
    const int*   ei  = (const int*)d_in[1];
    const float* W1  = (const float*)d_in[2];
    const float* as1 = (const float*)d_in[3];
    const float* ad1 = (const float*)d_in[4];
    const float* b1  = (const float*)d_in[5];
    const float* W2  = (const float*)d_in[6];
    const float* as2 = (const float*)d_in[7];
    const float* ad2 = (const float*)d_in[8];
    const float* b2  = (const float*)d_in[9];
    const float* Wfc = (const float*)d_in[10];
    const float* bfc = (const float*)d_in[11];
    float* out = (float*)d_out;

    float* f = (float*)d_ws;
    short* h2b   = (short*)f;                    // N*128 bf16
    float* s1    = f + 3200000;                  // N*8
    float* s2    = f + 3600000;                  // N*4
    float* wsv   = f + 3800000;                  // 27*8
    int*   rowptr= (int*)(f + 3810000);          // N+1
    int*   cursor= (int*)(f + 3870000);          // N
    int*   deg   = (int*)(f + 3930000);          // N
    int*   eidx  = (int*)(f + 3990000);          // E_TOT
    int*   bsum  = (int*)(f + 4340000);          // 256
    int*   bofs  = (int*)(f + 4341000);          // 256
    short* W1b   = (short*)(f + 4342000);        // 4*64*32 bf16
    short* W2bT  = (short*)(f + 4350000);        // 128*256 bf16

    // CSR build
    hipMemsetAsync(deg, 0, (size_t)N_NODES * 4, stream);
    k_hist<<<(E_TOT + 255) / 256, 256, 0, stream>>>(ei, deg);
    k_blocksum<<<SCAN_BLOCKS, 256, 0, stream>>>(deg, bsum);
    k_scanb<<<1, 256, 0, stream>>>(bsum, bofs);
    k_rowptr<<<SCAN_BLOCKS, 256, 0, stream>>>(deg, bofs, rowptr, cursor);
    k_scatter<<<(E_TOT + 255) / 256, 256, 0, stream>>>(ei, cursor, eidx);

    // weight prep + s1
    k_prep<<<128, 256, 0, stream>>>(W1, as1, ad1, W2, wsv, W1b, W2bT);
    k_s1<<<(N_NODES * 8 + 255) / 256, 256, 0, stream>>>(x, wsv, s1);

    // fused: layer-1 aggregation (x-space) + expand + GEMM2 -> h2b, s2
    k_fused1<<<3125, 256, 0, stream>>>(rowptr, eidx, x, s1, W1b, W2bT, b1,
                                       as2, ad2, h2b, s2);

    // layer-2 aggregation + final FC + sigmoid
    k_agg2_csr<<<12500, 256, 0, stream>>>(rowptr, eidx, s2, h2b, b2, Wfc, bfc, out);
}

// Round 17
// 188.974 us; speedup vs baseline: 2.1514x; 1.0494x over previous
//
#include <hip/hip_runtime.h>
#include <math.h>

#define N_NODES 50000
#define E_EDGES 300000
#define E_TOT   350000   // E + N self-loops
#define NEG 0.2f
#define EPS 1e-16f
#define SCAN_BLOCKS 196  // 196*256 = 50176 >= 50000

typedef __attribute__((ext_vector_type(8))) short bf16x8;
typedef __attribute__((ext_vector_type(4))) float f32x4;

__device__ __forceinline__ float leaky(float x) { return x > 0.f ? x : NEG * x; }
// fp32 -> bf16 (RNE, finite inputs)
__device__ __forceinline__ short f2bf(float v) {
    unsigned u = __float_as_uint(v);
    u += 0x7fffu + ((u >> 16) & 1u);
    return (short)(u >> 16);
}
__device__ __forceinline__ float bflo(unsigned u) { return __uint_as_float(u << 16); }
__device__ __forceinline__ float bfhi(unsigned u) { return __uint_as_float(u & 0xffff0000u); }

// ---------------- CSR construction (R11 proven) ----------------

__global__ __launch_bounds__(256) void k_hist(const int* __restrict__ ei,
        int* __restrict__ deg) {
    int e = blockIdx.x * 256 + threadIdx.x;
    if (e >= E_TOT) return;
    int d = (e < E_EDGES) ? ei[E_EDGES + e] : (e - E_EDGES);
    atomicAdd(&deg[d], 1);
}

__global__ __launch_bounds__(256) void k_blocksum(const int* __restrict__ deg,
        int* __restrict__ bsum) {
    int t = threadIdx.x;
    int idx = blockIdx.x * 256 + t;
    int v = (idx < N_NODES) ? deg[idx] : 0;
    #pragma unroll
    for (int off = 32; off > 0; off >>= 1) v += __shfl_down(v, off);
    __shared__ int ws[4];
    if ((t & 63) == 0) ws[t >> 6] = v;
    __syncthreads();
    if (t == 0) bsum[blockIdx.x] = ws[0] + ws[1] + ws[2] + ws[3];
}

__global__ __launch_bounds__(256) void k_scanb(const int* __restrict__ bsum,
        int* __restrict__ bofs) {
    __shared__ int sh[256];
    int t = threadIdx.x;
    sh[t] = (t < SCAN_BLOCKS) ? bsum[t] : 0;
    __syncthreads();
    for (int s = 1; s < 256; s <<= 1) {
        int v = (t >= s) ? sh[t - s] : 0;
        __syncthreads();
        sh[t] += v;
        __syncthreads();
    }
    bofs[t] = (t == 0) ? 0 : sh[t - 1];
}

__global__ __launch_bounds__(256) void k_rowptr(const int* __restrict__ deg,
        const int* __restrict__ bofs, int* __restrict__ rowptr,
        int* __restrict__ cursor) {
    __shared__ int sh[256];
    int t = threadIdx.x;
    int idx = blockIdx.x * 256 + t;
    int v = (idx < N_NODES) ? deg[idx] : 0;
    sh[t] = v;
    __syncthreads();
    for (int s = 1; s < 256; s <<= 1) {
        int u = (t >= s) ? sh[t - s] : 0;
        __syncthreads();
        sh[t] += u;
        __syncthreads();
    }
    int excl = sh[t] - v + bofs[blockIdx.x];
    if (idx < N_NODES) { rowptr[idx] = excl; cursor[idx] = excl; }
    if (idx == N_NODES) rowptr[N_NODES] = E_TOT;
}

__global__ __launch_bounds__(256) void k_scatter(const int* __restrict__ ei,
        int* __restrict__ cursor, int* __restrict__ eidx) {
    int e = blockIdx.x * 256 + threadIdx.x;
    if (e >= E_TOT) return;
    int s = (e < E_EDGES) ? ei[e] : (e - E_EDGES);
    int d = (e < E_EDGES) ? ei[E_EDGES + e] : (e - E_EDGES);
    int pos = atomicAdd(&cursor[d], 1);
    eidx[pos] = s;
}

// ---------------- prep: wsv = W1·a vectors, W1b (padded B^T), W2bT ----------

__global__ __launch_bounds__(256) void k_prep(const float* __restrict__ W1,
        const float* __restrict__ as1, const float* __restrict__ ad1,
        const float* __restrict__ W2, float* __restrict__ wsv,
        short* __restrict__ W1b, short* __restrict__ W2bT) {
    int t = blockIdx.x * 256 + threadIdx.x;      // grid 128 -> 32768 threads
    {
        int col = t >> 8, k = t & 255;
        W2bT[t] = f2bf(W2[k * 128 + col]);
    }
    if (t < 8192) {
        int h = t >> 11, col = (t >> 5) & 63, k = t & 31;
        W1b[t] = f2bf(k < 27 ? W1[k * 256 + h * 64 + col] : 0.f);
    }
    if (t < 216) {
        int k = t >> 3, j = t & 7;
        const float* av = (j < 4) ? (as1 + j * 64) : (ad1 + (j - 4) * 64);
        const float* wr = W1 + k * 256 + ((j & 3) * 64);
        float s = 0.f;
        for (int d = 0; d < 64; ++d) s += wr[d] * av[d];
        wsv[k * 8 + j] = s;
    }
}

// s1[n][0..3]=src half-scores, [4..7]=dst — direct from x via wsv (27->8 GEMV)
__global__ __launch_bounds__(256) void k_s1(const float* __restrict__ x,
        const float* __restrict__ wsv, float* __restrict__ s1) {
    int idx = blockIdx.x * 256 + threadIdx.x;    // grid 1563
    if (idx >= N_NODES * 8) return;
    int n = idx >> 3, j = idx & 7;
    float s = 0.f;
    #pragma unroll
    for (int k = 0; k < 27; ++k) s += x[n * 27 + k] * wsv[k * 8 + j];
    s1[idx] = s;
}

// ---------------- fused layer-1 agg (x-space) + expand + GEMM2 ----------------
// (R16 proven) Phase A: quarter-wave per node; Phase B/C MFMA.
__global__ __launch_bounds__(256) void k_fused1(const int* __restrict__ rowptr,
        const int* __restrict__ eidx, const float* __restrict__ x,
        const float* __restrict__ s1, const short* __restrict__ W1b,
        const short* __restrict__ W2bT, const float* __restrict__ b1,
        const float* __restrict__ as2, const float* __restrict__ ad2,
        short* __restrict__ h2b, float* __restrict__ s2) {
    __shared__ short LDSx[4 * 16 * 32];          // [head][m][k] bf16
    __shared__ short O[16 * 264];                // out1' [m][col], padded stride
    __shared__ float P[4][2][16];                // s2 partials [wave][ps/pd][m]
    int w = threadIdx.x >> 6, l = threadIdx.x & 63;
    int n0 = blockIdx.x * 16;                    // grid 3125 -> 50000 exact
    f32x4 z4 = {0.f, 0.f, 0.f, 0.f};

    // Phase A: group g (16 lanes) aggregates node n0+g
    {
        int g = threadIdx.x >> 4;                // 0..15
        int q = threadIdx.x & 15;                // lane in group = channel q
        int n = n0 + g;
        int beg = rowptr[n];
        int deg = rowptr[n + 1] - beg;
        float4 sdv = *(const float4*)(s1 + n * 8 + 4);
        bool cx1 = (q + 16) < 27;                // channel q+16 valid
        float a0 = 0.f, a1 = 0.f, a2 = 0.f, a3 = 0.f;   // channel q
        float b0 = 0.f, b1v = 0.f, b2v = 0.f, b3 = 0.f; // channel q+16
        float z0 = 0.f, z1 = 0.f, z2 = 0.f, z3 = 0.f;
        int i = 0;
        for (; i + 4 <= deg; i += 4) {
            int s0 = eidx[beg + i + 0];
            int s1i = eidx[beg + i + 1];
            int s2i = eidx[beg + i + 2];
            int s3 = eidx[beg + i + 3];
            float4 sv0 = *(const float4*)(s1 + s0 * 8);
            float4 sv1 = *(const float4*)(s1 + s1i * 8);
            float4 sv2 = *(const float4*)(s1 + s2i * 8);
            float4 sv3 = *(const float4*)(s1 + s3 * 8);
            float xa0 = x[s0 * 27 + q],  xb0 = cx1 ? x[s0 * 27 + q + 16] : 0.f;
            float xa1 = x[s1i * 27 + q], xb1 = cx1 ? x[s1i * 27 + q + 16] : 0.f;
            float xa2 = x[s2i * 27 + q], xb2 = cx1 ? x[s2i * 27 + q + 16] : 0.f;
            float xa3 = x[s3 * 27 + q],  xb3 = cx1 ? x[s3 * 27 + q + 16] : 0.f;
            float e00 = __expf(leaky(sv0.x + sdv.x));
            float e01 = __expf(leaky(sv0.y + sdv.y));
            float e02 = __expf(leaky(sv0.z + sdv.z));
            float e03 = __expf(leaky(sv0.w + sdv.w));
            float e10 = __expf(leaky(sv1.x + sdv.x));
            float e11 = __expf(leaky(sv1.y + sdv.y));
            float e12 = __expf(leaky(sv1.z + sdv.z));
            float e13 = __expf(leaky(sv1.w + sdv.w));
            float e20 = __expf(leaky(sv2.x + sdv.x));
            float e21 = __expf(leaky(sv2.y + sdv.y));
            float e22 = __expf(leaky(sv2.z + sdv.z));
            float e23 = __expf(leaky(sv2.w + sdv.w));
            float e30 = __expf(leaky(sv3.x + sdv.x));
            float e31 = __expf(leaky(sv3.y + sdv.y));
            float e32 = __expf(leaky(sv3.z + sdv.z));
            float e33 = __expf(leaky(sv3.w + sdv.w));
            z0 += e00 + e10 + e20 + e30;
            z1 += e01 + e11 + e21 + e31;
            z2 += e02 + e12 + e22 + e32;
            z3 += e03 + e13 + e23 + e33;
            a0 += e00 * xa0 + e10 * xa1 + e20 * xa2 + e30 * xa3;
            a1 += e01 * xa0 + e11 * xa1 + e21 * xa2 + e31 * xa3;
            a2 += e02 * xa0 + e12 * xa1 + e22 * xa2 + e32 * xa3;
            a3 += e03 * xa0 + e13 * xa1 + e23 * xa2 + e33 * xa3;
            b0  += e00 * xb0 + e10 * xb1 + e20 * xb2 + e30 * xb3;
            b1v += e01 * xb0 + e11 * xb1 + e21 * xb2 + e31 * xb3;
            b2v += e02 * xb0 + e12 * xb1 + e22 * xb2 + e32 * xb3;
            b3  += e03 * xb0 + e13 * xb1 + e23 * xb2 + e33 * xb3;
        }
        for (; i < deg; ++i) {
            int s0 = eidx[beg + i];
            float4 sv = *(const float4*)(s1 + s0 * 8);
            float xa = x[s0 * 27 + q];
            float xb = cx1 ? x[s0 * 27 + q + 16] : 0.f;
            float e0 = __expf(leaky(sv.x + sdv.x));
            float e1 = __expf(leaky(sv.y + sdv.y));
            float e2 = __expf(leaky(sv.z + sdv.z));
            float e3 = __expf(leaky(sv.w + sdv.w));
            z0 += e0; z1 += e1; z2 += e2; z3 += e3;
            a0 += e0 * xa; a1 += e1 * xa; a2 += e2 * xa; a3 += e3 * xa;
            b0 += e0 * xb; b1v += e1 * xb; b2v += e2 * xb; b3 += e3 * xb;
        }
        float i0 = 1.f / (z0 + EPS), i1 = 1.f / (z1 + EPS);
        float i2 = 1.f / (z2 + EPS), i3 = 1.f / (z3 + EPS);
        LDSx[0 * 512 + g * 32 + q] = f2bf(a0 * i0);
        LDSx[1 * 512 + g * 32 + q] = f2bf(a1 * i1);
        LDSx[2 * 512 + g * 32 + q] = f2bf(a2 * i2);
        LDSx[3 * 512 + g * 32 + q] = f2bf(a3 * i3);
        LDSx[0 * 512 + g * 32 + q + 16] = f2bf(b0 * i0);
        LDSx[1 * 512 + g * 32 + q + 16] = f2bf(b1v * i1);
        LDSx[2 * 512 + g * 32 + q + 16] = f2bf(b2v * i2);
        LDSx[3 * 512 + g * 32 + q + 16] = f2bf(b3 * i3);
    }
    __syncthreads();

    int lane16 = l & 15, quad = l >> 4;
    // Phase B: expand head w: [16x32] @ [32x64] -> elu -> O
    {
        bf16x8 a = *(const bf16x8*)&LDSx[w * 512 + lane16 * 32 + quad * 8];
        f32x4 cacc[4];
        #pragma unroll
        for (int nt = 0; nt < 4; ++nt) {
            bf16x8 b = *(const bf16x8*)&W1b[w * 2048 + (nt * 16 + lane16) * 32 + quad * 8];
            cacc[nt] = __builtin_amdgcn_mfma_f32_16x16x32_bf16(a, b, z4, 0, 0, 0);
        }
        #pragma unroll
        for (int nt = 0; nt < 4; ++nt) {
            int col = w * 64 + nt * 16 + lane16;
            float bb = b1[col];
            #pragma unroll
            for (int r2 = 0; r2 < 4; ++r2) {
                float v = cacc[nt][r2] + bb;
                v = v > 0.f ? v : __expf(v) - 1.f;
                O[(quad * 4 + r2) * 264 + col] = f2bf(v);
            }
        }
    }
    __syncthreads();

    // Phase C: gemm2, wave w -> h2 col-tiles {2w, 2w+1}
    f32x4 acc2[2];
    acc2[0] = z4; acc2[1] = z4;
    for (int k0 = 0; k0 < 256; k0 += 32) {
        bf16x8 a2 = *(const bf16x8*)&O[lane16 * 264 + k0 + quad * 8];
        #pragma unroll
        for (int j = 0; j < 2; ++j) {
            int ct = 2 * w + j;
            bf16x8 b2 = *(const bf16x8*)&W2bT[(ct * 16 + lane16) * 256 + k0 + quad * 8];
            acc2[j] = __builtin_amdgcn_mfma_f32_16x16x32_bf16(a2, b2, acc2[j], 0, 0, 0);
        }
    }
    float ps[4] = {0.f, 0.f, 0.f, 0.f}, pd[4] = {0.f, 0.f, 0.f, 0.f};
    #pragma unroll
    for (int j = 0; j < 2; ++j) {
        int col = (2 * w + j) * 16 + lane16;
        float a_s = as2[col], a_d = ad2[col];
        #pragma unroll
        for (int r2 = 0; r2 < 4; ++r2) {
            ps[r2] += acc2[j][r2] * a_s;
            pd[r2] += acc2[j][r2] * a_d;
            h2b[(n0 + quad * 4 + r2) * 128 + col] = f2bf(acc2[j][r2]);
        }
    }
    #pragma unroll
    for (int off = 1; off <= 8; off <<= 1)
        #pragma unroll
        for (int r2 = 0; r2 < 4; ++r2) {
            ps[r2] += __shfl_xor(ps[r2], off);
            pd[r2] += __shfl_xor(pd[r2], off);
        }
    if (lane16 == 0) {
        #pragma unroll
        for (int r2 = 0; r2 < 4; ++r2) {
            P[w][0][quad * 4 + r2] = ps[r2];
            P[w][1][quad * 4 + r2] = pd[r2];
        }
    }
    __syncthreads();
    if (threadIdx.x < 32) {
        int m = threadIdx.x & 15, hd = threadIdx.x >> 4;
        s2[(n0 + m) * 4 + hd]     = P[2 * hd][0][m] + P[2 * hd + 1][0][m];
        s2[(n0 + m) * 4 + 2 + hd] = P[2 * hd][1][m] + P[2 * hd + 1][1][m];
    }
}

// -------- layer-2 aggregate: 16-lane group per node, uint4 row loads ----
// Lane q covers channels 8q..8q+7 (head q>>3); 16 nodes/block, grid 3125.
__global__ __launch_bounds__(256) void k_agg2_csr(const int* __restrict__ rowptr,
        const int* __restrict__ eidx, const float* __restrict__ s2,
        const short* __restrict__ h2b, const float* __restrict__ b2,
        const float* __restrict__ Wfc, const float* __restrict__ bfc,
        float* __restrict__ out) {
    int g = threadIdx.x >> 4;                // 0..15
    int q = threadIdx.x & 15;
    int n = blockIdx.x * 16 + g;             // grid 3125 -> 50000 exact
    int beg = rowptr[n];
    int deg = rowptr[n + 1] - beg;
    int h = q >> 3;                          // head for channels 8q..8q+7
    float sd = s2[n * 4 + 2 + h];
    float4 accA = make_float4(0.f, 0.f, 0.f, 0.f);   // channels 8q..8q+3
    float4 accB = make_float4(0.f, 0.f, 0.f, 0.f);   // channels 8q+4..8q+7
    float z = 0.f;
    int i = 0;
    for (; i + 4 <= deg; i += 4) {
        int a0 = eidx[beg + i], a1 = eidx[beg + i + 1];
        int a2 = eidx[beg + i + 2], a3 = eidx[beg + i + 3];
        float e0 = __expf(leaky(s2[a0 * 4 + h] + sd));
        float e1 = __expf(leaky(s2[a1 * 4 + h] + sd));
        float e2 = __expf(leaky(s2[a2 * 4 + h] + sd));
        float e3 = __expf(leaky(s2[a3 * 4 + h] + sd));
        uint4 v0 = *(const uint4*)(h2b + a0 * 128 + q * 8);
        uint4 v1 = *(const uint4*)(h2b + a1 * 128 + q * 8);
        uint4 v2 = *(const uint4*)(h2b + a2 * 128 + q * 8);
        uint4 v3 = *(const uint4*)(h2b + a3 * 128 + q * 8);
        z += e0 + e1 + e2 + e3;
        accA.x += e0 * bflo(v0.x) + e1 * bflo(v1.x) + e2 * bflo(v2.x) + e3 * bflo(v3.x);
        accA.y += e0 * bfhi(v0.x) + e1 * bfhi(v1.x) + e2 * bfhi(v2.x) + e3 * bfhi(v3.x);
        accA.z += e0 * bflo(v0.y) + e1 * bflo(v1.y) + e2 * bflo(v2.y) + e3 * bflo(v3.y);
        accA.w += e0 * bfhi(v0.y) + e1 * bfhi(v1.y) + e2 * bfhi(v2.y) + e3 * bfhi(v3.y);
        accB.x += e0 * bflo(v0.z) + e1 * bflo(v1.z) + e2 * bflo(v2.z) + e3 * bflo(v3.z);
        accB.y += e0 * bfhi(v0.z) + e1 * bfhi(v1.z) + e2 * bfhi(v2.z) + e3 * bfhi(v3.z);
        accB.z += e0 * bflo(v0.w) + e1 * bflo(v1.w) + e2 * bflo(v2.w) + e3 * bflo(v3.w);
        accB.w += e0 * bfhi(v0.w) + e1 * bfhi(v1.w) + e2 * bfhi(v2.w) + e3 * bfhi(v3.w);
    }
    for (; i < deg; ++i) {
        int a0 = eidx[beg + i];
        float e0 = __expf(leaky(s2[a0 * 4 + h] + sd));
        uint4 v0 = *(const uint4*)(h2b + a0 * 128 + q * 8);
        z += e0;
        accA.x += e0 * bflo(v0.x); accA.y += e0 * bfhi(v0.x);
        accA.z += e0 * bflo(v0.y); accA.w += e0 * bfhi(v0.y);
        accB.x += e0 * bflo(v0.z); accB.y += e0 * bfhi(v0.z);
        accB.z += e0 * bflo(v0.w); accB.w += e0 * bfhi(v0.w);
    }
    float inv = 1.f / (z + EPS);
    int c0 = q * 8;
    float p = 0.f;
    float va[8] = {accA.x, accA.y, accA.z, accA.w, accB.x, accB.y, accB.z, accB.w};
    #pragma unroll
    for (int j = 0; j < 8; ++j) {
        float v = va[j] * inv + b2[c0 + j];
        v = v > 0.f ? v : __expf(v) - 1.f;
        p += v * Wfc[c0 + j];
    }
    #pragma unroll
    for (int off = 1; off <= 8; off <<= 1) p += __shfl_xor(p, off);
    if (q == 0) out[n] = 1.f / (1.f + __expf(-(p + bfc[0])));
}

extern "C" void kernel_launch(void* const* d_in, const int* in_sizes, int n_in,
                              void* d_out, int out_size, void* d_ws, size_t ws_size,
                              hipStream_t stream) {
    const float* x   = (const float*)d_in[0];
    const int*   ei  = (const int*)d_in[1];
    const float* W1  = (const float*)d_in[2];
    const float* as1 = (const float*)d_in[3];
    const float* ad1 = (const float*)d_in[4];
    const float* b1  = (const float*)d_in[5];
    const float* W2  = (const float*)d_in[6];
    const float* as2 = (const float*)d_in[7];
    const float* ad2 = (const float*)d_in[8];
    const float* b2  = (const float*)d_in[9];
    const float* Wfc = (const float*)d_in[10];
    const float* bfc = (const float*)d_in[11];
    float* out = (float*)d_out;

    float* f = (float*)d_ws;
    short* h2b   = (short*)f;                    // N*128 bf16
    float* s1    = f + 3200000;                  // N*8
    float* s2    = f + 3600000;                  // N*4
    float* wsv   = f + 3800000;                  // 27*8
    int*   rowptr= (int*)(f + 3810000);          // N+1
    int*   cursor= (int*)(f + 3870000);          // N
    int*   deg   = (int*)(f + 3930000);          // N
    int*   eidx  = (int*)(f + 3990000);          // E_TOT
    int*   bsum  = (int*)(f + 4340000);          // 256
    int*   bofs  = (int*)(f + 4341000);          // 256
    short* W1b   = (short*)(f + 4342000);        // 4*64*32 bf16
    short* W2bT  = (short*)(f + 4350000);        // 128*256 bf16

    // CSR build
    hipMemsetAsync(deg, 0, (size_t)N_NODES * 4, stream);
    k_hist<<<(E_TOT + 255) / 256, 256, 0, stream>>>(ei, deg);
    k_blocksum<<<SCAN_BLOCKS, 256, 0, stream>>>(deg, bsum);
    k_scanb<<<1, 256, 0, stream>>>(bsum, bofs);
    k_rowptr<<<SCAN_BLOCKS, 256, 0, stream>>>(deg, bofs, rowptr, cursor);
    k_scatter<<<(E_TOT + 255) / 256, 256, 0, stream>>>(ei, cursor, eidx);

    // weight prep + s1
    k_prep<<<128, 256, 0, stream>>>(W1, as1, ad1, W2, wsv, W1b, W2bT);
    k_s1<<<(N_NODES * 8 + 255) / 256, 256, 0, stream>>>(x, wsv, s1);

    // fused: layer-1 aggregation (x-space) + expand + GEMM2 -> h2b, s2
    k_fused1<<<3125, 256, 0, stream>>>(rowptr, eidx, x, s1, W1b, W2bT, b1,
                                       as2, ad2, h2b, s2);

    // layer-2 aggregation + final FC + sigmoid
    k_agg2_csr<<<3125, 256, 0, stream>>>(rowptr, eidx, s2, h2b, b2, Wfc, bfc, out);
}